// Round 5
// baseline (133.049 us; speedup 1.0000x reference)
//
#include <hip/hip_runtime.h>
#include <hip/hip_bf16.h>

typedef __attribute__((ext_vector_type(8))) short short8;
typedef __attribute__((ext_vector_type(8))) unsigned short ushort8;
typedef __attribute__((ext_vector_type(4))) float f32x4;
typedef __attribute__((ext_vector_type(2))) float f32x2;
typedef __attribute__((ext_vector_type(4))) unsigned int uint4v;

#define DIM 128
#define EPS 1e-6f

__device__ __forceinline__ float wave_sum(float v){
  #pragma unroll
  for (int m = 32; m >= 1; m >>= 1) v += __shfl_xor(v, m);
  return v;
}

// One launch: block 0 = u1/u2/c12; blocks 1..64 = W^T bf16; blocks 65.. = row_ptr.
__global__ void setup_kernel(const float* __restrict__ w_W,
                             const float* __restrict__ w1_W, const float* __restrict__ w1_b,
                             const float* __restrict__ w2_W, const float* __restrict__ w2_b,
                             const int* __restrict__ adj_row,
                             __hip_bfloat16* __restrict__ wt_bf,
                             float* __restrict__ u1, float* __restrict__ u2,
                             float* __restrict__ c12,
                             int* __restrict__ row_ptr, int N, int E){
  const int b = blockIdx.x, tid = threadIdx.x;
  if (b == 0){
    if (tid < DIM){
      float s1 = 0.f, s2 = 0.f;
      for (int j = 0; j < DIM; ++j){ s1 += w1_W[tid*DIM + j]; s2 += w2_W[tid*DIM + j]; }
      u1[tid] = s1; u2[tid] = s2;
    }
    if (tid < 64){
      float c1 = w1_b[tid] + w1_b[tid + 64];
      float c2 = w2_b[tid] + w2_b[tid + 64];
      c1 = wave_sum(c1); c2 = wave_sum(c2);
      if (tid == 0){ c12[0] = c1; c12[1] = c2; }
    }
  } else if (b <= 64){
    int idx = (b - 1) * 256 + tid;
    int j = idx >> 7, d = idx & 127;
    wt_bf[idx] = __float2bfloat16(w_W[d*DIM + j]);
  } else {
    int r = (b - 65) * 256 + tid;
    if (r <= N){
      int lo = 0, hi = E;
      while (lo < hi){ int mid = (lo + hi) >> 1; if (adj_row[mid] < r) lo = mid + 1; else hi = mid; }
      row_ptr[r] = lo;
    }
  }
}

// LN1 (16-lane group per node) + value = q@w_W + w_b (bf16 MFMA; wave = 32 rows x 64 cols)
__launch_bounds__(256)
__global__ void node_kernel(const float* __restrict__ query,
                            const __hip_bfloat16* __restrict__ wt_bf,
                            const float* __restrict__ w_b,
                            const float* __restrict__ ln1_g, const float* __restrict__ ln1_b,
                            const float* __restrict__ u1, const float* __restrict__ u2,
                            const float* __restrict__ c12,
                            __hip_bfloat16* __restrict__ value,
                            float* __restrict__ sum1, float* __restrict__ sum2, int N){
  __shared__ __hip_bfloat16 A[64][136];    // +8 pad; row stride 272B (16B aligned)
  const int tid  = threadIdx.x;
  const int lane = tid & 63;
  const int w    = tid >> 6;
  const int q16  = lane >> 4;    // group 0..3
  const int lq   = lane & 15;    // lane in group
  const int base = blockIdx.x * 64;

  float uu1[8], uu2[8], gg[8], bv[8];
  {
    const float* p1 = u1 + lq*8; const float* p2 = u2 + lq*8;
    const float* pg = ln1_g + lq*8; const float* pb = ln1_b + lq*8;
    #pragma unroll
    for (int j = 0; j < 8; ++j){ uu1[j]=p1[j]; uu2[j]=p2[j]; gg[j]=pg[j]; bv[j]=pb[j]; }
  }
  const float c1 = c12[0], c2 = c12[1];

  // LN1: group q16 of wave w handles node base + w*16 + it*4 + q16
  #pragma unroll
  for (int it = 0; it < 4; ++it){
    const int row = w*16 + it*4 + q16;
    const int n   = base + row;
    float x[8];
    if (n < N){
      const float* qp = query + (size_t)n*DIM + lq*8;
      #pragma unroll
      for (int j = 0; j < 8; ++j) x[j] = qp[j];
    } else {
      #pragma unroll
      for (int j = 0; j < 8; ++j) x[j] = 0.f;
    }
    float s = 0.f, s2 = 0.f;
    #pragma unroll
    for (int j = 0; j < 8; ++j){ s += x[j]; s2 += x[j]*x[j]; }
    #pragma unroll
    for (int m = 1; m <= 8; m <<= 1){ s += __shfl_xor(s, m); s2 += __shfl_xor(s2, m); }
    const float mean = s * (1.f/128.f);
    const float var  = s2 * (1.f/128.f) - mean*mean;
    const float rs   = rsqrtf(var + EPS);

    float p1 = 0.f, p2 = 0.f;
    unsigned pk[4];
    #pragma unroll
    for (int j = 0; j < 4; ++j){
      float n0 = gg[2*j]   * (x[2*j]   - mean) * rs + bv[2*j];
      float n1 = gg[2*j+1] * (x[2*j+1] - mean) * rs + bv[2*j+1];
      p1 += n0*uu1[2*j] + n1*uu1[2*j+1];
      p2 += n0*uu2[2*j] + n1*uu2[2*j+1];
      union { __hip_bfloat16 h; unsigned short u; } a_, b_;
      a_.h = __float2bfloat16(n0); b_.h = __float2bfloat16(n1);
      pk[j] = ((unsigned)b_.u << 16) | (unsigned)a_.u;
    }
    uint4v pv = { pk[0], pk[1], pk[2], pk[3] };
    *(uint4v*)&A[row][lq*8] = pv;
    #pragma unroll
    for (int m = 1; m <= 8; m <<= 1){ p1 += __shfl_xor(p1, m); p2 += __shfl_xor(p2, m); }
    if (lq == 0 && n < N){
      sum1[n] = tanhf(p1 + c1);
      sum2[n] = tanhf(p2 + c2);
    }
  }
  __syncthreads();

  // GEMM: wave w: rows [(w&1)*32, +32) x cols [(w>>1)*64, +64); 2 MFMA per B-load
  const int rh = (w & 1) * 32;
  const int ch = (w >> 1) * 64;
  short8 afr[2][4];
  #pragma unroll
  for (int m = 0; m < 2; ++m)
    #pragma unroll
    for (int ks = 0; ks < 4; ++ks)
      afr[m][ks] = *(const short8*)&A[rh + m*16 + lq][ks*32 + q16*8];
  __syncthreads();   // all waves done reading A before C overwrites it

  #pragma unroll
  for (int jj = 0; jj < 4; ++jj){
    const int colb = ch + jj*16;
    f32x4 acc[2];
    acc[0] = (f32x4){0.f,0.f,0.f,0.f};
    acc[1] = (f32x4){0.f,0.f,0.f,0.f};
    #pragma unroll
    for (int ks = 0; ks < 4; ++ks){
      short8 bfr = *(const short8*)(wt_bf + (size_t)(colb + lq)*DIM + ks*32 + q16*8);
      acc[0] = __builtin_amdgcn_mfma_f32_16x16x32_bf16(afr[0][ks], bfr, acc[0], 0, 0, 0);
      acc[1] = __builtin_amdgcn_mfma_f32_16x16x32_bf16(afr[1][ks], bfr, acc[1], 0, 0, 0);
    }
    const int col  = colb + lq;            // C/D: col = lane&15, row = (lane>>4)*4 + reg
    const float bias = w_b[col];
    #pragma unroll
    for (int m = 0; m < 2; ++m)
      #pragma unroll
      for (int i = 0; i < 4; ++i)
        A[rh + m*16 + q16*4 + i][col] = __float2bfloat16(acc[m][i] + bias);
  }
  __syncthreads();

  // coalesced bf16 row stores: 256 threads = 64 rows x 4 segs of 32 elems
  const int row = tid >> 2, seg = tid & 3;
  const int n = base + row;
  if (n < N){
    ushort8* dst = (ushort8*)((unsigned short*)value + (size_t)n*DIM + seg*32);
    #pragma unroll
    for (int j = 0; j < 4; ++j)
      dst[j] = *(const ushort8*)&A[row][seg*32 + j*8];
  }
}

// Per-edge weight precompute: excol[e] = {exp(leaky(av*(s1[row]+s2[col]))), col}
__global__ void pack_kernel(const float* __restrict__ adj_val, const int* __restrict__ adj_row,
                            const int* __restrict__ adj_col,
                            const float* __restrict__ sum1, const float* __restrict__ sum2,
                            float2* __restrict__ excol, int E){
  int e = blockIdx.x * 256 + threadIdx.x;
  if (e >= E) return;
  float av = adj_val[e];
  int r = adj_row[e], c = adj_col[e];
  float x = av * (sum1[r] + sum2[c]);
  float lg = x > 0.f ? x : 0.2f * x;
  excol[e] = make_float2(__expf(lg), __int_as_float(c));
}

// One wave per row; single pass (LN2 scale-invariance cancels softmax 1/s).
// Quarter q: edges e0+q, e0+q+4, ... via broadcast 8B excol; v_pk_fma_f32 accumulate;
// single-pass LN2 stats (Sx, Sxx) with 16-lane reduce. Tail: wk=0, ck=0 -> +0.
__launch_bounds__(256)
__global__ void edge_kernel(const float2* __restrict__ excol, const int* __restrict__ row_ptr,
                            const __hip_bfloat16* __restrict__ value,
                            const float* __restrict__ ln2_g, const float* __restrict__ ln2_b,
                            float* __restrict__ out, int N){
  const int lane = threadIdx.x & 63;
  const int r = blockIdx.x * 4 + (threadIdx.x >> 6);
  if (r >= N) return;
  const int e0 = row_ptr[r], e1 = row_ptr[r+1];
  const int q  = lane >> 4;   // quarter
  const int lq = lane & 15;   // owns dims [8*lq, 8*lq+8)
  const unsigned int* vp32 = (const unsigned int*)value;

  f32x2 acc2[4];
  #pragma unroll
  for (int j = 0; j < 4; ++j) acc2[j] = (f32x2){0.f, 0.f};

  for (int eb = e0 + q; eb < e1; eb += 16){
    #pragma unroll
    for (int t = 0; t < 4; ++t){
      const int e  = eb + t*4;
      const int ee = min(e, e1 - 1);
      float2 ecv = excol[ee];
      const float wk = (e < e1) ? ecv.x : 0.f;
      const int   ck = (e < e1) ? __float_as_int(ecv.y) : 0;
      uint4v v = *(const uint4v*)(vp32 + ((size_t)ck << 6) + lq*4);
      f32x2 w2 = { wk, wk };
      #pragma unroll
      for (int jw = 0; jw < 4; ++jw){
        f32x2 v2 = { __uint_as_float(v[jw] << 16),
                     __uint_as_float(v[jw] & 0xffff0000u) };
        asm("v_pk_fma_f32 %0, %1, %2, %0" : "+v"(acc2[jw]) : "v"(v2), "v"(w2));
      }
    }
  }

  // reduce across quarters (dims replicated 4x across wave)
  #pragma unroll
  for (int j = 0; j < 4; ++j){
    acc2[j].x += __shfl_xor(acc2[j].x, 16); acc2[j].y += __shfl_xor(acc2[j].y, 16);
    acc2[j].x += __shfl_xor(acc2[j].x, 32); acc2[j].y += __shfl_xor(acc2[j].y, 32);
  }

  // single-pass LN2 stats over 16 lanes (each dim once per quarter)
  float sx = 0.f, sxx = 0.f;
  #pragma unroll
  for (int j = 0; j < 4; ++j){
    sx  += acc2[j].x + acc2[j].y;
    sxx += acc2[j].x*acc2[j].x + acc2[j].y*acc2[j].y;
  }
  #pragma unroll
  for (int m = 1; m <= 8; m <<= 1){ sx += __shfl_xor(sx, m); sxx += __shfl_xor(sxx, m); }
  const float mean = sx * (1.f/128.f);
  const float var  = sxx * (1.f/128.f) - mean*mean;
  const float rs   = rsqrtf(var + EPS);

  if (q == 0){
    float4 g0 = ((const float4*)ln2_g)[lq*2], g1 = ((const float4*)ln2_g)[lq*2+1];
    float4 b0 = ((const float4*)ln2_b)[lq*2], b1 = ((const float4*)ln2_b)[lq*2+1];
    float4 o0, o1;
    o0.x = g0.x*(acc2[0].x-mean)*rs + b0.x; o0.y = g0.y*(acc2[0].y-mean)*rs + b0.y;
    o0.z = g0.z*(acc2[1].x-mean)*rs + b0.z; o0.w = g0.w*(acc2[1].y-mean)*rs + b0.w;
    o1.x = g1.x*(acc2[2].x-mean)*rs + b1.x; o1.y = g1.y*(acc2[2].y-mean)*rs + b1.y;
    o1.z = g1.z*(acc2[3].x-mean)*rs + b1.z; o1.w = g1.w*(acc2[3].y-mean)*rs + b1.w;
    float4* op = (float4*)(out + (size_t)r*DIM + lq*8);
    op[0] = o0; op[1] = o1;
  }
}

extern "C" void kernel_launch(void* const* d_in, const int* in_sizes, int n_in,
                              void* d_out, int out_size, void* d_ws, size_t ws_size,
                              hipStream_t stream){
  const float* query   = (const float*)d_in[0];
  const float* adj_val = (const float*)d_in[1];
  const float* w_W     = (const float*)d_in[2];
  const float* w_b     = (const float*)d_in[3];
  const float* w1_W    = (const float*)d_in[4];
  const float* w1_b    = (const float*)d_in[5];
  const float* w2_W    = (const float*)d_in[6];
  const float* w2_b    = (const float*)d_in[7];
  const float* ln1_g   = (const float*)d_in[8];
  const float* ln1_b   = (const float*)d_in[9];
  const float* ln2_g   = (const float*)d_in[10];
  const float* ln2_b   = (const float*)d_in[11];
  const int*   adj_row = (const int*)d_in[12];
  const int*   adj_col = (const int*)d_in[13];

  const int N = in_sizes[0] / DIM;
  const int E = in_sizes[1];

  char* ws = (char*)d_ws;
  size_t off = 0;
  __hip_bfloat16* value = (__hip_bfloat16*)(ws + off); off += (size_t)N * DIM * 2;
  float* sum1   = (float*)(ws + off); off += (size_t)N * 4;
  float* sum2   = (float*)(ws + off); off += (size_t)N * 4;
  int* row_ptr  = (int*)(ws + off);   off += (size_t)(N + 2) * 4;
  float* u1     = (float*)(ws + off); off += DIM * 4;
  float* u2     = (float*)(ws + off); off += DIM * 4;
  float* c12    = (float*)(ws + off); off += 2 * 4;
  off = (off + 63) & ~(size_t)63;
  __hip_bfloat16* wt_bf = (__hip_bfloat16*)(ws + off); off += DIM * DIM * 2;
  off = (off + 63) & ~(size_t)63;
  float2* excol = (float2*)(ws + off);

  const int rp_blocks = (N + 1 + 255) / 256;
  setup_kernel<<<65 + rp_blocks, 256, 0, stream>>>(w_W, w1_W, w1_b, w2_W, w2_b, adj_row,
                                                   wt_bf, u1, u2, c12, row_ptr, N, E);
  node_kernel<<<(N + 63) / 64, 256, 0, stream>>>(query, wt_bf, w_b, ln1_g, ln1_b,
                                                 u1, u2, c12, value, sum1, sum2, N);
  pack_kernel<<<(E + 255) / 256, 256, 0, stream>>>(adj_val, adj_row, adj_col,
                                                   sum1, sum2, excol, E);
  edge_kernel<<<(N + 3) / 4, 256, 0, stream>>>(excol, row_ptr, value,
                                               ln2_g, ln2_b, (float*)d_out, N);
}

// Round 6
// 114.634 us; speedup vs baseline: 1.1606x; 1.1606x over previous
//
#include <hip/hip_runtime.h>
#include <hip/hip_bf16.h>

typedef __attribute__((ext_vector_type(8))) short short8;
typedef __attribute__((ext_vector_type(8))) unsigned short ushort8;
typedef __attribute__((ext_vector_type(4))) float f32x4;
typedef __attribute__((ext_vector_type(4))) unsigned int uint4v;

#define DIM 128
#define EPS 1e-6f

__device__ __forceinline__ float wave_sum(float v){
  #pragma unroll
  for (int m = 32; m >= 1; m >>= 1) v += __shfl_xor(v, m);
  return v;
}

// One launch: block 0 = u1/u2/c12; blocks 1..64 = W^T bf16; blocks 65.. = row_ptr.
__global__ void setup_kernel(const float* __restrict__ w_W,
                             const float* __restrict__ w1_W, const float* __restrict__ w1_b,
                             const float* __restrict__ w2_W, const float* __restrict__ w2_b,
                             const int* __restrict__ adj_row,
                             __hip_bfloat16* __restrict__ wt_bf,
                             float* __restrict__ u1, float* __restrict__ u2,
                             float* __restrict__ c12,
                             int* __restrict__ row_ptr, int N, int E){
  const int b = blockIdx.x, tid = threadIdx.x;
  if (b == 0){
    if (tid < DIM){
      float s1 = 0.f, s2 = 0.f;
      for (int j = 0; j < DIM; ++j){ s1 += w1_W[tid*DIM + j]; s2 += w2_W[tid*DIM + j]; }
      u1[tid] = s1; u2[tid] = s2;
    }
    if (tid < 64){
      float c1 = w1_b[tid] + w1_b[tid + 64];
      float c2 = w2_b[tid] + w2_b[tid + 64];
      c1 = wave_sum(c1); c2 = wave_sum(c2);
      if (tid == 0){ c12[0] = c1; c12[1] = c2; }
    }
  } else if (b <= 64){
    int idx = (b - 1) * 256 + tid;
    int j = idx >> 7, d = idx & 127;
    wt_bf[idx] = __float2bfloat16(w_W[d*DIM + j]);
  } else {
    int r = (b - 65) * 256 + tid;
    if (r <= N){
      int lo = 0, hi = E;
      while (lo < hi){ int mid = (lo + hi) >> 1; if (adj_row[mid] < r) lo = mid + 1; else hi = mid; }
      row_ptr[r] = lo;
    }
  }
}

// LN1 (16-lane group per node) + value = q@w_W + w_b (bf16 MFMA; wave = 32 rows x 64 cols)
// + per-row int8 quantization of value (scale folded into pack via s_val).
__launch_bounds__(256)
__global__ void node_kernel(const float* __restrict__ query,
                            const __hip_bfloat16* __restrict__ wt_bf,
                            const float* __restrict__ w_b,
                            const float* __restrict__ ln1_g, const float* __restrict__ ln1_b,
                            const float* __restrict__ u1, const float* __restrict__ u2,
                            const float* __restrict__ c12,
                            unsigned char* __restrict__ value_q,
                            float* __restrict__ s_val,
                            float* __restrict__ sum1, float* __restrict__ sum2, int N){
  __shared__ __hip_bfloat16 A[64][136];    // +8 pad; row stride 272B (16B aligned)
  const int tid  = threadIdx.x;
  const int lane = tid & 63;
  const int w    = tid >> 6;
  const int q16  = lane >> 4;    // group 0..3
  const int lq   = lane & 15;    // lane in group
  const int base = blockIdx.x * 64;

  float uu1[8], uu2[8], gg[8], bv[8];
  {
    const float* p1 = u1 + lq*8; const float* p2 = u2 + lq*8;
    const float* pg = ln1_g + lq*8; const float* pb = ln1_b + lq*8;
    #pragma unroll
    for (int j = 0; j < 8; ++j){ uu1[j]=p1[j]; uu2[j]=p2[j]; gg[j]=pg[j]; bv[j]=pb[j]; }
  }
  const float c1 = c12[0], c2 = c12[1];

  // LN1: group q16 of wave w handles node base + w*16 + it*4 + q16
  #pragma unroll
  for (int it = 0; it < 4; ++it){
    const int row = w*16 + it*4 + q16;
    const int n   = base + row;
    float x[8];
    if (n < N){
      const float* qp = query + (size_t)n*DIM + lq*8;
      #pragma unroll
      for (int j = 0; j < 8; ++j) x[j] = qp[j];
    } else {
      #pragma unroll
      for (int j = 0; j < 8; ++j) x[j] = 0.f;
    }
    float s = 0.f, s2 = 0.f;
    #pragma unroll
    for (int j = 0; j < 8; ++j){ s += x[j]; s2 += x[j]*x[j]; }
    #pragma unroll
    for (int m = 1; m <= 8; m <<= 1){ s += __shfl_xor(s, m); s2 += __shfl_xor(s2, m); }
    const float mean = s * (1.f/128.f);
    const float var  = s2 * (1.f/128.f) - mean*mean;
    const float rs   = rsqrtf(var + EPS);

    float p1 = 0.f, p2 = 0.f;
    unsigned pk[4];
    #pragma unroll
    for (int j = 0; j < 4; ++j){
      float n0 = gg[2*j]   * (x[2*j]   - mean) * rs + bv[2*j];
      float n1 = gg[2*j+1] * (x[2*j+1] - mean) * rs + bv[2*j+1];
      p1 += n0*uu1[2*j] + n1*uu1[2*j+1];
      p2 += n0*uu2[2*j] + n1*uu2[2*j+1];
      union { __hip_bfloat16 h; unsigned short u; } a_, b_;
      a_.h = __float2bfloat16(n0); b_.h = __float2bfloat16(n1);
      pk[j] = ((unsigned)b_.u << 16) | (unsigned)a_.u;
    }
    uint4v pv = { pk[0], pk[1], pk[2], pk[3] };
    *(uint4v*)&A[row][lq*8] = pv;
    #pragma unroll
    for (int m = 1; m <= 8; m <<= 1){ p1 += __shfl_xor(p1, m); p2 += __shfl_xor(p2, m); }
    if (lq == 0 && n < N){
      sum1[n] = tanhf(p1 + c1);
      sum2[n] = tanhf(p2 + c2);
    }
  }
  __syncthreads();

  // GEMM: wave w: rows [(w&1)*32, +32) x cols [(w>>1)*64, +64); 2 MFMA per B-load
  const int rh = (w & 1) * 32;
  const int ch = (w >> 1) * 64;
  short8 afr[2][4];
  #pragma unroll
  for (int m = 0; m < 2; ++m)
    #pragma unroll
    for (int ks = 0; ks < 4; ++ks)
      afr[m][ks] = *(const short8*)&A[rh + m*16 + lq][ks*32 + q16*8];
  __syncthreads();   // all waves done reading A before C overwrites it

  #pragma unroll
  for (int jj = 0; jj < 4; ++jj){
    const int colb = ch + jj*16;
    f32x4 acc[2];
    acc[0] = (f32x4){0.f,0.f,0.f,0.f};
    acc[1] = (f32x4){0.f,0.f,0.f,0.f};
    #pragma unroll
    for (int ks = 0; ks < 4; ++ks){
      short8 bfr = *(const short8*)(wt_bf + (size_t)(colb + lq)*DIM + ks*32 + q16*8);
      acc[0] = __builtin_amdgcn_mfma_f32_16x16x32_bf16(afr[0][ks], bfr, acc[0], 0, 0, 0);
      acc[1] = __builtin_amdgcn_mfma_f32_16x16x32_bf16(afr[1][ks], bfr, acc[1], 0, 0, 0);
    }
    const int col  = colb + lq;            // C/D: col = lane&15, row = (lane>>4)*4 + reg
    const float bias = w_b[col];
    #pragma unroll
    for (int m = 0; m < 2; ++m)
      #pragma unroll
      for (int i = 0; i < 4; ++i)
        A[rh + m*16 + q16*4 + i][col] = __float2bfloat16(acc[m][i] + bias);
  }
  __syncthreads();

  // int8 quantize + store: 4 threads per row (tid>>2 = row, tid&3 = seg of 32 elems)
  const int row = tid >> 2, seg = tid & 3;
  const int n = base + row;
  float vals[32];
  float amax = 0.f;
  #pragma unroll
  for (int j = 0; j < 32; ++j){
    vals[j] = __bfloat162float(A[row][seg*32 + j]);
    amax = fmaxf(amax, fabsf(vals[j]));
  }
  amax = fmaxf(amax, __shfl_xor(amax, 1));
  amax = fmaxf(amax, __shfl_xor(amax, 2));
  const float qs = amax > 0.f ? 127.f / amax : 0.f;
  if (n < N){
    if (seg == 0) s_val[n] = amax * (1.f/127.f);
    unsigned dw[8];
    #pragma unroll
    for (int d = 0; d < 8; ++d){
      unsigned q0 = (unsigned)__float2int_rn(fmaf(vals[4*d+0], qs, 128.f));
      unsigned q1 = (unsigned)__float2int_rn(fmaf(vals[4*d+1], qs, 128.f));
      unsigned q2 = (unsigned)__float2int_rn(fmaf(vals[4*d+2], qs, 128.f));
      unsigned q3 = (unsigned)__float2int_rn(fmaf(vals[4*d+3], qs, 128.f));
      dw[d] = q0 | (q1 << 8) | (q2 << 16) | (q3 << 24);
    }
    uint4v* dst = (uint4v*)(value_q + (size_t)n*DIM + seg*32);
    dst[0] = (uint4v){dw[0], dw[1], dw[2], dw[3]};
    dst[1] = (uint4v){dw[4], dw[5], dw[6], dw[7]};
  }
}

// Per-edge: excol[e] = {exp(leaky(av*(s1[row]+s2[col]))) * s_val[col], col}
__global__ void pack_kernel(const float* __restrict__ adj_val, const int* __restrict__ adj_row,
                            const int* __restrict__ adj_col,
                            const float* __restrict__ sum1, const float* __restrict__ sum2,
                            const float* __restrict__ s_val,
                            float2* __restrict__ excol, int E){
  int e = blockIdx.x * 256 + threadIdx.x;
  if (e >= E) return;
  float av = adj_val[e];
  int r = adj_row[e], c = adj_col[e];
  float x = av * (sum1[r] + sum2[c]);
  float lg = x > 0.f ? x : 0.2f * x;
  excol[e] = make_float2(__expf(lg) * s_val[c], __int_as_float(c));
}

// One wave per row; single pass (LN2 scale-invariance cancels softmax 1/s).
// Quarter q: edges e0+q, e0+q+4, ...; broadcast 8B excol read; 8B int8 gather;
// ubyte unpack (v_cvt_f32_ubyte). +128 offset removed via sumw before LN2 stats.
// Tail slots: ws=0, ck=0 -> +0. (No inline asm / no clamp — R5 lesson: they
// serialize the gathers.)
__launch_bounds__(256)
__global__ void edge_kernel(const float2* __restrict__ excol, const int* __restrict__ row_ptr,
                            const unsigned char* __restrict__ value_q,
                            const float* __restrict__ ln2_g, const float* __restrict__ ln2_b,
                            float* __restrict__ out, int N){
  const int lane = threadIdx.x & 63;
  const int r = blockIdx.x * 4 + (threadIdx.x >> 6);
  if (r >= N) return;
  const int e0 = row_ptr[r], e1 = row_ptr[r+1];
  const int q  = lane >> 4;   // quarter
  const int lq = lane & 15;   // owns dims [8*lq, 8*lq+8)

  float acc[8];
  #pragma unroll
  for (int j = 0; j < 8; ++j) acc[j] = 0.f;
  float sumw = 0.f;

  for (int eb = e0 + q; eb < e1; eb += 16){
    #pragma unroll
    for (int t = 0; t < 4; ++t){
      const int e = eb + t*4;
      float2 ecv = (e < e1) ? excol[e] : make_float2(0.f, __int_as_float(0));
      const float ws = ecv.x;
      const int   ck = __float_as_int(ecv.y);
      uint2 v = *(const uint2*)(value_q + ((size_t)ck << 7) + lq*8);
      sumw += ws;
      acc[0] += ws * (float)( v.x        & 0xff);
      acc[1] += ws * (float)((v.x >>  8) & 0xff);
      acc[2] += ws * (float)((v.x >> 16) & 0xff);
      acc[3] += ws * (float)( v.x >> 24);
      acc[4] += ws * (float)( v.y        & 0xff);
      acc[5] += ws * (float)((v.y >>  8) & 0xff);
      acc[6] += ws * (float)((v.y >> 16) & 0xff);
      acc[7] += ws * (float)( v.y >> 24);
    }
  }

  // reduce across quarters (dims replicated 4x across wave)
  #pragma unroll
  for (int j = 0; j < 8; ++j){
    acc[j] += __shfl_xor(acc[j], 16);
    acc[j] += __shfl_xor(acc[j], 32);
  }
  sumw += __shfl_xor(sumw, 16);
  sumw += __shfl_xor(sumw, 32);

  // remove the +128 quant offset (uniform across dims; avoids f32 cancellation)
  const float bias = 128.f * sumw;
  #pragma unroll
  for (int j = 0; j < 8; ++j) acc[j] -= bias;

  // single-pass LN2 stats over 16 lanes (each dim once per quarter)
  float sx = 0.f, sxx = 0.f;
  #pragma unroll
  for (int j = 0; j < 8; ++j){ sx += acc[j]; sxx += acc[j]*acc[j]; }
  #pragma unroll
  for (int m = 1; m <= 8; m <<= 1){ sx += __shfl_xor(sx, m); sxx += __shfl_xor(sxx, m); }
  const float mean = sx * (1.f/128.f);
  const float var  = sxx * (1.f/128.f) - mean*mean;
  const float rs   = rsqrtf(var + EPS);

  if (q == 0){
    float4 g0 = ((const float4*)ln2_g)[lq*2], g1 = ((const float4*)ln2_g)[lq*2+1];
    float4 b0 = ((const float4*)ln2_b)[lq*2], b1 = ((const float4*)ln2_b)[lq*2+1];
    float4 o0, o1;
    o0.x = g0.x*(acc[0]-mean)*rs + b0.x; o0.y = g0.y*(acc[1]-mean)*rs + b0.y;
    o0.z = g0.z*(acc[2]-mean)*rs + b0.z; o0.w = g0.w*(acc[3]-mean)*rs + b0.w;
    o1.x = g1.x*(acc[4]-mean)*rs + b1.x; o1.y = g1.y*(acc[5]-mean)*rs + b1.y;
    o1.z = g1.z*(acc[6]-mean)*rs + b1.z; o1.w = g1.w*(acc[7]-mean)*rs + b1.w;
    float4* op = (float4*)(out + (size_t)r*DIM + lq*8);
    op[0] = o0; op[1] = o1;
  }
}

extern "C" void kernel_launch(void* const* d_in, const int* in_sizes, int n_in,
                              void* d_out, int out_size, void* d_ws, size_t ws_size,
                              hipStream_t stream){
  const float* query   = (const float*)d_in[0];
  const float* adj_val = (const float*)d_in[1];
  const float* w_W     = (const float*)d_in[2];
  const float* w_b     = (const float*)d_in[3];
  const float* w1_W    = (const float*)d_in[4];
  const float* w1_b    = (const float*)d_in[5];
  const float* w2_W    = (const float*)d_in[6];
  const float* w2_b    = (const float*)d_in[7];
  const float* ln1_g   = (const float*)d_in[8];
  const float* ln1_b   = (const float*)d_in[9];
  const float* ln2_g   = (const float*)d_in[10];
  const float* ln2_b   = (const float*)d_in[11];
  const int*   adj_row = (const int*)d_in[12];
  const int*   adj_col = (const int*)d_in[13];

  const int N = in_sizes[0] / DIM;
  const int E = in_sizes[1];

  char* ws = (char*)d_ws;
  size_t off = 0;
  unsigned char* value_q = (unsigned char*)(ws + off); off += (size_t)N * DIM;
  float* s_val  = (float*)(ws + off); off += (size_t)N * 4;
  float* sum1   = (float*)(ws + off); off += (size_t)N * 4;
  float* sum2   = (float*)(ws + off); off += (size_t)N * 4;
  int* row_ptr  = (int*)(ws + off);   off += (size_t)(N + 2) * 4;
  float* u1     = (float*)(ws + off); off += DIM * 4;
  float* u2     = (float*)(ws + off); off += DIM * 4;
  float* c12    = (float*)(ws + off); off += 2 * 4;
  off = (off + 63) & ~(size_t)63;
  __hip_bfloat16* wt_bf = (__hip_bfloat16*)(ws + off); off += DIM * DIM * 2;
  off = (off + 63) & ~(size_t)63;
  float2* excol = (float2*)(ws + off);

  const int rp_blocks = (N + 1 + 255) / 256;
  setup_kernel<<<65 + rp_blocks, 256, 0, stream>>>(w_W, w1_W, w1_b, w2_W, w2_b, adj_row,
                                                   wt_bf, u1, u2, c12, row_ptr, N, E);
  node_kernel<<<(N + 63) / 64, 256, 0, stream>>>(query, wt_bf, w_b, ln1_g, ln1_b,
                                                 u1, u2, c12, value_q, s_val,
                                                 sum1, sum2, N);
  pack_kernel<<<(E + 255) / 256, 256, 0, stream>>>(adj_val, adj_row, adj_col,
                                                   sum1, sum2, s_val, excol, E);
  edge_kernel<<<(N + 3) / 4, 256, 0, stream>>>(excol, row_ptr, value_q,
                                               ln2_g, ln2_b, (float*)d_out, N);
}

// Round 7
// 106.416 us; speedup vs baseline: 1.2503x; 1.0772x over previous
//
#include <hip/hip_runtime.h>
#include <hip/hip_bf16.h>

typedef __attribute__((ext_vector_type(8))) short short8;
typedef __attribute__((ext_vector_type(8))) unsigned short ushort8;
typedef __attribute__((ext_vector_type(4))) float f32x4;
typedef __attribute__((ext_vector_type(2))) float f32x2;
typedef __attribute__((ext_vector_type(4))) unsigned int uint4v;

#define DIM 128
#define EPS 1e-6f

__device__ __forceinline__ float wave_sum(float v){
  #pragma unroll
  for (int m = 32; m >= 1; m >>= 1) v += __shfl_xor(v, m);
  return v;
}

// One launch: block 0 = u1/u2/c12; blocks 1..64 = W^T bf16. (row_ptr moved to pack.)
__global__ void setup_kernel(const float* __restrict__ w_W,
                             const float* __restrict__ w1_W, const float* __restrict__ w1_b,
                             const float* __restrict__ w2_W, const float* __restrict__ w2_b,
                             __hip_bfloat16* __restrict__ wt_bf,
                             float* __restrict__ u1, float* __restrict__ u2,
                             float* __restrict__ c12){
  const int b = blockIdx.x, tid = threadIdx.x;
  if (b == 0){
    if (tid < DIM){
      float s1 = 0.f, s2 = 0.f;
      for (int j = 0; j < DIM; ++j){ s1 += w1_W[tid*DIM + j]; s2 += w2_W[tid*DIM + j]; }
      u1[tid] = s1; u2[tid] = s2;
    }
    if (tid < 64){
      float c1 = w1_b[tid] + w1_b[tid + 64];
      float c2 = w2_b[tid] + w2_b[tid + 64];
      c1 = wave_sum(c1); c2 = wave_sum(c2);
      if (tid == 0){ c12[0] = c1; c12[1] = c2; }
    }
  } else {
    int idx = (b - 1) * 256 + tid;
    int j = idx >> 7, d = idx & 127;
    wt_bf[idx] = __float2bfloat16(w_W[d*DIM + j]);
  }
}

// LN1 (16-lane group per node) + value = q@w_W + w_b (bf16 MFMA; wave = 32 rows x 64 cols)
// + per-row int8 quantization of value. Writes sum1, s2v = {tanh2, scale}.
__launch_bounds__(256)
__global__ void node_kernel(const float* __restrict__ query,
                            const __hip_bfloat16* __restrict__ wt_bf,
                            const float* __restrict__ w_b,
                            const float* __restrict__ ln1_g, const float* __restrict__ ln1_b,
                            const float* __restrict__ u1, const float* __restrict__ u2,
                            const float* __restrict__ c12,
                            unsigned char* __restrict__ value_q,
                            float* __restrict__ sum1, float2* __restrict__ s2v, int N){
  __shared__ __hip_bfloat16 A[64][136];    // +8 pad; row stride 272B (16B aligned)
  const int tid  = threadIdx.x;
  const int lane = tid & 63;
  const int w    = tid >> 6;
  const int q16  = lane >> 4;    // group 0..3
  const int lq   = lane & 15;    // lane in group
  const int base = blockIdx.x * 64;

  float uu1[8], uu2[8], gg[8], bv[8];
  {
    const float* p1 = u1 + lq*8; const float* p2 = u2 + lq*8;
    const float* pg = ln1_g + lq*8; const float* pb = ln1_b + lq*8;
    #pragma unroll
    for (int j = 0; j < 8; ++j){ uu1[j]=p1[j]; uu2[j]=p2[j]; gg[j]=pg[j]; bv[j]=pb[j]; }
  }
  const float c1 = c12[0], c2 = c12[1];

  // LN1: group q16 of wave w handles node base + w*16 + it*4 + q16
  #pragma unroll
  for (int it = 0; it < 4; ++it){
    const int row = w*16 + it*4 + q16;
    const int n   = base + row;
    float x[8];
    if (n < N){
      const float* qp = query + (size_t)n*DIM + lq*8;
      #pragma unroll
      for (int j = 0; j < 8; ++j) x[j] = qp[j];
    } else {
      #pragma unroll
      for (int j = 0; j < 8; ++j) x[j] = 0.f;
    }
    float s = 0.f, s2 = 0.f;
    #pragma unroll
    for (int j = 0; j < 8; ++j){ s += x[j]; s2 += x[j]*x[j]; }
    #pragma unroll
    for (int m = 1; m <= 8; m <<= 1){ s += __shfl_xor(s, m); s2 += __shfl_xor(s2, m); }
    const float mean = s * (1.f/128.f);
    const float var  = s2 * (1.f/128.f) - mean*mean;
    const float rs   = rsqrtf(var + EPS);

    float p1 = 0.f, p2 = 0.f;
    unsigned pk[4];
    #pragma unroll
    for (int j = 0; j < 4; ++j){
      float n0 = gg[2*j]   * (x[2*j]   - mean) * rs + bv[2*j];
      float n1 = gg[2*j+1] * (x[2*j+1] - mean) * rs + bv[2*j+1];
      p1 += n0*uu1[2*j] + n1*uu1[2*j+1];
      p2 += n0*uu2[2*j] + n1*uu2[2*j+1];
      union { __hip_bfloat16 h; unsigned short u; } a_, b_;
      a_.h = __float2bfloat16(n0); b_.h = __float2bfloat16(n1);
      pk[j] = ((unsigned)b_.u << 16) | (unsigned)a_.u;
    }
    uint4v pv = { pk[0], pk[1], pk[2], pk[3] };
    *(uint4v*)&A[row][lq*8] = pv;
    #pragma unroll
    for (int m = 1; m <= 8; m <<= 1){ p1 += __shfl_xor(p1, m); p2 += __shfl_xor(p2, m); }
    if (lq == 0 && n < N){
      sum1[n]   = tanhf(p1 + c1);
      s2v[n].x  = tanhf(p2 + c2);
    }
  }
  __syncthreads();

  // GEMM: wave w: rows [(w&1)*32, +32) x cols [(w>>1)*64, +64); 2 MFMA per B-load
  const int rh = (w & 1) * 32;
  const int ch = (w >> 1) * 64;
  short8 afr[2][4];
  #pragma unroll
  for (int m = 0; m < 2; ++m)
    #pragma unroll
    for (int ks = 0; ks < 4; ++ks)
      afr[m][ks] = *(const short8*)&A[rh + m*16 + lq][ks*32 + q16*8];
  __syncthreads();   // all waves done reading A before C overwrites it

  #pragma unroll
  for (int jj = 0; jj < 4; ++jj){
    const int colb = ch + jj*16;
    f32x4 acc[2];
    acc[0] = (f32x4){0.f,0.f,0.f,0.f};
    acc[1] = (f32x4){0.f,0.f,0.f,0.f};
    #pragma unroll
    for (int ks = 0; ks < 4; ++ks){
      short8 bfr = *(const short8*)(wt_bf + (size_t)(colb + lq)*DIM + ks*32 + q16*8);
      acc[0] = __builtin_amdgcn_mfma_f32_16x16x32_bf16(afr[0][ks], bfr, acc[0], 0, 0, 0);
      acc[1] = __builtin_amdgcn_mfma_f32_16x16x32_bf16(afr[1][ks], bfr, acc[1], 0, 0, 0);
    }
    const int col  = colb + lq;            // C/D: col = lane&15, row = (lane>>4)*4 + reg
    const float bias = w_b[col];
    #pragma unroll
    for (int m = 0; m < 2; ++m)
      #pragma unroll
      for (int i = 0; i < 4; ++i)
        A[rh + m*16 + q16*4 + i][col] = __float2bfloat16(acc[m][i] + bias);
  }
  __syncthreads();

  // int8 quantize + store: 4 threads per row; vectorized ds_read_b128 (16B x4)
  const int row = tid >> 2, seg = tid & 3;
  const int n = base + row;
  float vals[32];
  float amax = 0.f;
  const ushort8* ap = (const ushort8*)&A[row][seg*32];
  #pragma unroll
  for (int h = 0; h < 4; ++h){
    ushort8 vv = ap[h];
    #pragma unroll
    for (int j = 0; j < 8; ++j){
      float f = __uint_as_float((unsigned)vv[j] << 16);
      vals[h*8 + j] = f;
      amax = fmaxf(amax, fabsf(f));
    }
  }
  amax = fmaxf(amax, __shfl_xor(amax, 1));
  amax = fmaxf(amax, __shfl_xor(amax, 2));
  const float qs = amax > 0.f ? 127.f / amax : 0.f;
  if (n < N){
    if (seg == 0) s2v[n].y = amax * (1.f/127.f);
    unsigned dw[8];
    #pragma unroll
    for (int d = 0; d < 8; ++d){
      unsigned q0 = (unsigned)__float2int_rn(fmaf(vals[4*d+0], qs, 128.f));
      unsigned q1 = (unsigned)__float2int_rn(fmaf(vals[4*d+1], qs, 128.f));
      unsigned q2 = (unsigned)__float2int_rn(fmaf(vals[4*d+2], qs, 128.f));
      unsigned q3 = (unsigned)__float2int_rn(fmaf(vals[4*d+3], qs, 128.f));
      dw[d] = q0 | (q1 << 8) | (q2 << 16) | (q3 << 24);
    }
    uint4v* dst = (uint4v*)(value_q + (size_t)n*DIM + seg*32);
    dst[0] = (uint4v){dw[0], dw[1], dw[2], dw[3]};
    dst[1] = (uint4v){dw[4], dw[5], dw[6], dw[7]};
  }
}

// Per-edge: row_ptr via boundary detect (adj_row sorted) + excol = {ws, byteoff}
// ws = exp(leaky(av*(s1[r]+s2[c]))) * s_val[c];  byteoff = c*128 (pre-shifted).
__global__ void pack_kernel(const float* __restrict__ adj_val, const int* __restrict__ adj_row,
                            const int* __restrict__ adj_col,
                            const float* __restrict__ sum1, const float2* __restrict__ s2v,
                            float2* __restrict__ excol, int* __restrict__ row_ptr,
                            int N, int E){
  int e = blockIdx.x * 256 + threadIdx.x;
  if (e >= E) return;
  int r  = adj_row[e];
  int rp = (e > 0) ? adj_row[e-1] : -1;
  if (rp != r){
    for (int rr = rp + 1; rr <= r; ++rr) row_ptr[rr] = e;
  }
  if (e == E - 1){
    for (int rr = r + 1; rr <= N; ++rr) row_ptr[rr] = E;
  }
  float av = adj_val[e];
  int c = adj_col[e];
  float2 sv = s2v[c];          // one 8B gather: {tanh2, scale}
  float x = av * (sum1[r] + sv.x);
  float lg = x > 0.f ? x : 0.2f * x;
  excol[e] = make_float2(__expf(lg) * sv.y, __int_as_float(c << 7));
}

// One wave per row; single pass (LN2 scale-invariance cancels softmax 1/s).
// Quarter q: edges e0+q, e0+q+4, ...; broadcast 8B excol; 8B int8 gather (pre-shifted
// byte offset); ubyte unpack; float2 vector FMAs (v_pk_fma candidate, NO asm).
// +128 quant offset removed via sumw before LN2 stats. Tail: ws=0, off=0 -> +0.
__launch_bounds__(256)
__global__ void edge_kernel(const float2* __restrict__ excol, const int* __restrict__ row_ptr,
                            const unsigned char* __restrict__ value_q,
                            const float* __restrict__ ln2_g, const float* __restrict__ ln2_b,
                            float* __restrict__ out, int N){
  const int lane = threadIdx.x & 63;
  const int r = blockIdx.x * 4 + (threadIdx.x >> 6);
  if (r >= N) return;
  const int e0 = row_ptr[r], e1 = row_ptr[r+1];
  const int q  = lane >> 4;   // quarter
  const int lq = lane & 15;   // owns dims [8*lq, 8*lq+8)
  const unsigned char* vbase = value_q + lq*8;

  f32x2 acc2[4];
  #pragma unroll
  for (int j = 0; j < 4; ++j) acc2[j] = (f32x2){0.f, 0.f};
  float sumw = 0.f;

  for (int eb = e0 + q; eb < e1; eb += 16){
    #pragma unroll
    for (int t = 0; t < 4; ++t){
      const int e = eb + t*4;
      float2 ecv = (e < e1) ? excol[e] : make_float2(0.f, __int_as_float(0));
      const float wsc = ecv.x;
      const unsigned voff = (unsigned)__float_as_int(ecv.y);
      uint2 v = *(const uint2*)(vbase + voff);
      sumw += wsc;
      f32x2 w2 = { wsc, wsc };
      f32x2 p0 = { (float)( v.x        & 0xff), (float)((v.x >>  8) & 0xff) };
      f32x2 p1 = { (float)((v.x >> 16) & 0xff), (float)( v.x >> 24)         };
      f32x2 p2 = { (float)( v.y        & 0xff), (float)((v.y >>  8) & 0xff) };
      f32x2 p3 = { (float)((v.y >> 16) & 0xff), (float)( v.y >> 24)         };
      acc2[0] += w2 * p0;
      acc2[1] += w2 * p1;
      acc2[2] += w2 * p2;
      acc2[3] += w2 * p3;
    }
  }

  // reduce across quarters (dims replicated 4x across wave)
  #pragma unroll
  for (int j = 0; j < 4; ++j){
    acc2[j].x += __shfl_xor(acc2[j].x, 16); acc2[j].y += __shfl_xor(acc2[j].y, 16);
    acc2[j].x += __shfl_xor(acc2[j].x, 32); acc2[j].y += __shfl_xor(acc2[j].y, 32);
  }
  sumw += __shfl_xor(sumw, 16);
  sumw += __shfl_xor(sumw, 32);

  // remove the +128 quant offset (uniform across dims; avoids f32 cancellation)
  const float bias = 128.f * sumw;
  #pragma unroll
  for (int j = 0; j < 4; ++j){ acc2[j].x -= bias; acc2[j].y -= bias; }

  // single-pass LN2 stats over 16 lanes (each dim once per quarter)
  float sx = 0.f, sxx = 0.f;
  #pragma unroll
  for (int j = 0; j < 4; ++j){
    sx  += acc2[j].x + acc2[j].y;
    sxx += acc2[j].x*acc2[j].x + acc2[j].y*acc2[j].y;
  }
  #pragma unroll
  for (int m = 1; m <= 8; m <<= 1){ sx += __shfl_xor(sx, m); sxx += __shfl_xor(sxx, m); }
  const float mean = sx * (1.f/128.f);
  const float var  = sxx * (1.f/128.f) - mean*mean;
  const float rs   = rsqrtf(var + EPS);

  if (q == 0){
    float4 g0 = ((const float4*)ln2_g)[lq*2], g1 = ((const float4*)ln2_g)[lq*2+1];
    float4 b0 = ((const float4*)ln2_b)[lq*2], b1 = ((const float4*)ln2_b)[lq*2+1];
    float4 o0, o1;
    o0.x = g0.x*(acc2[0].x-mean)*rs + b0.x; o0.y = g0.y*(acc2[0].y-mean)*rs + b0.y;
    o0.z = g0.z*(acc2[1].x-mean)*rs + b0.z; o0.w = g0.w*(acc2[1].y-mean)*rs + b0.w;
    o1.x = g1.x*(acc2[2].x-mean)*rs + b1.x; o1.y = g1.y*(acc2[2].y-mean)*rs + b1.y;
    o1.z = g1.z*(acc2[3].x-mean)*rs + b1.z; o1.w = g1.w*(acc2[3].y-mean)*rs + b1.w;
    float4* op = (float4*)(out + (size_t)r*DIM + lq*8);
    op[0] = o0; op[1] = o1;
  }
}

extern "C" void kernel_launch(void* const* d_in, const int* in_sizes, int n_in,
                              void* d_out, int out_size, void* d_ws, size_t ws_size,
                              hipStream_t stream){
  const float* query   = (const float*)d_in[0];
  const float* adj_val = (const float*)d_in[1];
  const float* w_W     = (const float*)d_in[2];
  const float* w_b     = (const float*)d_in[3];
  const float* w1_W    = (const float*)d_in[4];
  const float* w1_b    = (const float*)d_in[5];
  const float* w2_W    = (const float*)d_in[6];
  const float* w2_b    = (const float*)d_in[7];
  const float* ln1_g   = (const float*)d_in[8];
  const float* ln1_b   = (const float*)d_in[9];
  const float* ln2_g   = (const float*)d_in[10];
  const float* ln2_b   = (const float*)d_in[11];
  const int*   adj_row = (const int*)d_in[12];
  const int*   adj_col = (const int*)d_in[13];

  const int N = in_sizes[0] / DIM;
  const int E = in_sizes[1];

  char* ws = (char*)d_ws;
  size_t off = 0;
  unsigned char* value_q = (unsigned char*)(ws + off); off += (size_t)N * DIM;
  float* sum1   = (float*)(ws + off); off += (size_t)N * 4;
  float2* s2v   = (float2*)(ws + off); off += (size_t)N * 8;
  int* row_ptr  = (int*)(ws + off);   off += (size_t)(N + 2) * 4;
  float* u1     = (float*)(ws + off); off += DIM * 4;
  float* u2     = (float*)(ws + off); off += DIM * 4;
  float* c12    = (float*)(ws + off); off += 2 * 4;
  off = (off + 63) & ~(size_t)63;
  __hip_bfloat16* wt_bf = (__hip_bfloat16*)(ws + off); off += DIM * DIM * 2;
  off = (off + 63) & ~(size_t)63;
  float2* excol = (float2*)(ws + off);

  setup_kernel<<<65, 256, 0, stream>>>(w_W, w1_W, w1_b, w2_W, w2_b, wt_bf, u1, u2, c12);
  node_kernel<<<(N + 63) / 64, 256, 0, stream>>>(query, wt_bf, w_b, ln1_g, ln1_b,
                                                 u1, u2, c12, value_q, sum1, s2v, N);
  pack_kernel<<<(E + 255) / 256, 256, 0, stream>>>(adj_val, adj_row, adj_col,
                                                   sum1, s2v, excol, row_ptr, N, E);
  edge_kernel<<<(N + 3) / 4, 256, 0, stream>>>(excol, row_ptr, value_q,
                                               ln2_g, ln2_b, (float*)d_out, N);
}

// Round 8
// 105.596 us; speedup vs baseline: 1.2600x; 1.0078x over previous
//
#include <hip/hip_runtime.h>
#include <hip/hip_bf16.h>

typedef __attribute__((ext_vector_type(8))) short short8;
typedef __attribute__((ext_vector_type(8))) unsigned short ushort8;
typedef __attribute__((ext_vector_type(4))) float f32x4;
typedef __attribute__((ext_vector_type(2))) float f32x2;
typedef __attribute__((ext_vector_type(4))) unsigned int uint4v;

#define DIM 128
#define EPS 1e-6f

__device__ __forceinline__ float wave_sum(float v){
  #pragma unroll
  for (int m = 32; m >= 1; m >>= 1) v += __shfl_xor(v, m);
  return v;
}

// One launch: block 0 = u1/u2/c12; blocks 1..64 = W^T bf16.
__global__ void setup_kernel(const float* __restrict__ w_W,
                             const float* __restrict__ w1_W, const float* __restrict__ w1_b,
                             const float* __restrict__ w2_W, const float* __restrict__ w2_b,
                             __hip_bfloat16* __restrict__ wt_bf,
                             float* __restrict__ u1, float* __restrict__ u2,
                             float* __restrict__ c12){
  const int b = blockIdx.x, tid = threadIdx.x;
  if (b == 0){
    __shared__ float p1s[256], p2s[256];
    const int d = tid & 127, half = tid >> 7;       // half 0: j 0..63, half 1: j 64..127
    const float4* w1p = (const float4*)(w1_W + d*DIM + half*64);
    const float4* w2p = (const float4*)(w2_W + d*DIM + half*64);
    float s1 = 0.f, s2 = 0.f;
    #pragma unroll 4
    for (int j = 0; j < 16; ++j){
      float4 a = w1p[j]; s1 += (a.x + a.y) + (a.z + a.w);
      float4 c = w2p[j]; s2 += (c.x + c.y) + (c.z + c.w);
    }
    p1s[tid] = s1; p2s[tid] = s2;
    __syncthreads();
    if (tid < 128){ u1[tid] = p1s[tid] + p1s[tid+128]; u2[tid] = p2s[tid] + p2s[tid+128]; }
    if (tid < 64){
      float c1 = w1_b[tid] + w1_b[tid + 64];
      float c2 = w2_b[tid] + w2_b[tid + 64];
      c1 = wave_sum(c1); c2 = wave_sum(c2);
      if (tid == 0){ c12[0] = c1; c12[1] = c2; }
    }
  } else {
    int idx = (b - 1) * 256 + tid;
    int j = idx >> 7, d = idx & 127;
    wt_bf[idx] = __float2bfloat16(w_W[d*DIM + j]);
  }
}

// LN1 (16-lane group per node, all 4 query rows prefetched) + value = q@w_W + w_b
// (bf16 MFMA; wave = 32 rows x 64 cols) + per-row int8 quantization.
__launch_bounds__(256)
__global__ void node_kernel(const float* __restrict__ query,
                            const __hip_bfloat16* __restrict__ wt_bf,
                            const float* __restrict__ w_b,
                            const float* __restrict__ ln1_g, const float* __restrict__ ln1_b,
                            const float* __restrict__ u1, const float* __restrict__ u2,
                            const float* __restrict__ c12,
                            unsigned char* __restrict__ value_q,
                            float* __restrict__ sum1, float2* __restrict__ s2v, int N){
  __shared__ __hip_bfloat16 A[64][136];    // +8 pad; row stride 272B (16B aligned)
  const int tid  = threadIdx.x;
  const int lane = tid & 63;
  const int w    = tid >> 6;
  const int q16  = lane >> 4;    // group 0..3
  const int lq   = lane & 15;    // lane in group
  const int base = blockIdx.x * 64;

  float uu1[8], uu2[8], gg[8], bv[8];
  {
    const float* p1 = u1 + lq*8; const float* p2 = u2 + lq*8;
    const float* pg = ln1_g + lq*8; const float* pb = ln1_b + lq*8;
    #pragma unroll
    for (int j = 0; j < 8; ++j){ uu1[j]=p1[j]; uu2[j]=p2[j]; gg[j]=pg[j]; bv[j]=pb[j]; }
  }
  const float c1 = c12[0], c2 = c12[1];

  // prefetch all 4 LN1 rows (4 independent load pairs in flight)
  float x[4][8];
  #pragma unroll
  for (int it = 0; it < 4; ++it){
    const int n = base + w*16 + it*4 + q16;
    if (n < N){
      const float4* qp = (const float4*)(query + (size_t)n*DIM + lq*8);
      float4 a = qp[0], b = qp[1];
      x[it][0]=a.x; x[it][1]=a.y; x[it][2]=a.z; x[it][3]=a.w;
      x[it][4]=b.x; x[it][5]=b.y; x[it][6]=b.z; x[it][7]=b.w;
    } else {
      #pragma unroll
      for (int j = 0; j < 8; ++j) x[it][j] = 0.f;
    }
  }

  #pragma unroll
  for (int it = 0; it < 4; ++it){
    const int row = w*16 + it*4 + q16;
    const int n   = base + row;
    float s = 0.f, s2 = 0.f;
    #pragma unroll
    for (int j = 0; j < 8; ++j){ s += x[it][j]; s2 += x[it][j]*x[it][j]; }
    #pragma unroll
    for (int m = 1; m <= 8; m <<= 1){ s += __shfl_xor(s, m); s2 += __shfl_xor(s2, m); }
    const float mean = s * (1.f/128.f);
    const float var  = s2 * (1.f/128.f) - mean*mean;
    const float rs   = rsqrtf(var + EPS);

    float p1 = 0.f, p2 = 0.f;
    unsigned pk[4];
    #pragma unroll
    for (int j = 0; j < 4; ++j){
      float n0 = gg[2*j]   * (x[it][2*j]   - mean) * rs + bv[2*j];
      float n1 = gg[2*j+1] * (x[it][2*j+1] - mean) * rs + bv[2*j+1];
      p1 += n0*uu1[2*j] + n1*uu1[2*j+1];
      p2 += n0*uu2[2*j] + n1*uu2[2*j+1];
      union { __hip_bfloat16 h; unsigned short u; } a_, b_;
      a_.h = __float2bfloat16(n0); b_.h = __float2bfloat16(n1);
      pk[j] = ((unsigned)b_.u << 16) | (unsigned)a_.u;
    }
    uint4v pv = { pk[0], pk[1], pk[2], pk[3] };
    *(uint4v*)&A[row][lq*8] = pv;
    #pragma unroll
    for (int m = 1; m <= 8; m <<= 1){ p1 += __shfl_xor(p1, m); p2 += __shfl_xor(p2, m); }
    if (lq == 0 && n < N){
      sum1[n]   = tanhf(p1 + c1);
      s2v[n].x  = tanhf(p2 + c2);
    }
  }
  __syncthreads();

  // GEMM: wave w: rows [(w&1)*32, +32) x cols [(w>>1)*64, +64); 2 MFMA per B-load
  const int rh = (w & 1) * 32;
  const int ch = (w >> 1) * 64;
  short8 afr[2][4];
  #pragma unroll
  for (int m = 0; m < 2; ++m)
    #pragma unroll
    for (int ks = 0; ks < 4; ++ks)
      afr[m][ks] = *(const short8*)&A[rh + m*16 + lq][ks*32 + q16*8];
  __syncthreads();   // all waves done reading A before C overwrites it

  #pragma unroll
  for (int jj = 0; jj < 4; ++jj){
    const int colb = ch + jj*16;
    f32x4 acc[2];
    acc[0] = (f32x4){0.f,0.f,0.f,0.f};
    acc[1] = (f32x4){0.f,0.f,0.f,0.f};
    #pragma unroll
    for (int ks = 0; ks < 4; ++ks){
      short8 bfr = *(const short8*)(wt_bf + (size_t)(colb + lq)*DIM + ks*32 + q16*8);
      acc[0] = __builtin_amdgcn_mfma_f32_16x16x32_bf16(afr[0][ks], bfr, acc[0], 0, 0, 0);
      acc[1] = __builtin_amdgcn_mfma_f32_16x16x32_bf16(afr[1][ks], bfr, acc[1], 0, 0, 0);
    }
    const int col  = colb + lq;            // C/D: col = lane&15, row = (lane>>4)*4 + reg
    const float bias = w_b[col];
    #pragma unroll
    for (int m = 0; m < 2; ++m)
      #pragma unroll
      for (int i = 0; i < 4; ++i)
        A[rh + m*16 + q16*4 + i][col] = __float2bfloat16(acc[m][i] + bias);
  }
  __syncthreads();

  // int8 quantize + store: 4 threads per row; vectorized ds_read_b128 (16B x4)
  const int row = tid >> 2, seg = tid & 3;
  const int n = base + row;
  float vals[32];
  float amax = 0.f;
  const ushort8* ap = (const ushort8*)&A[row][seg*32];
  #pragma unroll
  for (int h = 0; h < 4; ++h){
    ushort8 vv = ap[h];
    #pragma unroll
    for (int j = 0; j < 8; ++j){
      float f = __uint_as_float((unsigned)vv[j] << 16);
      vals[h*8 + j] = f;
      amax = fmaxf(amax, fabsf(f));
    }
  }
  amax = fmaxf(amax, __shfl_xor(amax, 1));
  amax = fmaxf(amax, __shfl_xor(amax, 2));
  const float qs = amax > 0.f ? 127.f / amax : 0.f;
  if (n < N){
    if (seg == 0) s2v[n].y = amax * (1.f/127.f);
    unsigned dw[8];
    #pragma unroll
    for (int d = 0; d < 8; ++d){
      unsigned q0 = (unsigned)__float2int_rn(fmaf(vals[4*d+0], qs, 128.f));
      unsigned q1 = (unsigned)__float2int_rn(fmaf(vals[4*d+1], qs, 128.f));
      unsigned q2 = (unsigned)__float2int_rn(fmaf(vals[4*d+2], qs, 128.f));
      unsigned q3 = (unsigned)__float2int_rn(fmaf(vals[4*d+3], qs, 128.f));
      dw[d] = q0 | (q1 << 8) | (q2 << 16) | (q3 << 24);
    }
    uint4v* dst = (uint4v*)(value_q + (size_t)n*DIM + seg*32);
    dst[0] = (uint4v){dw[0], dw[1], dw[2], dw[3]};
    dst[1] = (uint4v){dw[4], dw[5], dw[6], dw[7]};
  }
}

// Per-edge (2 edges/thread): row_ptr via boundary detect (adj_row sorted) +
// excol = {ws, byteoff}; ws = exp(leaky(av*(s1[r]+s2[c]))) * s_val[c]; byteoff = c*128.
__global__ void pack_kernel(const float* __restrict__ adj_val, const int* __restrict__ adj_row,
                            const int* __restrict__ adj_col,
                            const float* __restrict__ sum1, const float2* __restrict__ s2v,
                            float2* __restrict__ excol, int* __restrict__ row_ptr,
                            int N, int E){
  const int e2 = (blockIdx.x * 256 + threadIdx.x) * 2;
  if (e2 >= E) return;
  const int2 rr = *(const int2*)(adj_row + e2);
  const int rp = (e2 > 0) ? adj_row[e2 - 1] : -1;
  if (rp != rr.x)
    for (int t = rp + 1; t <= rr.x; ++t) row_ptr[t] = e2;

  const float2 av = *(const float2*)(adj_val + e2);
  const int2   cc = *(const int2*)(adj_col + e2);
  const float2 sv0 = s2v[cc.x];
  const float s10 = sum1[rr.x];

  float x0 = av.x * (s10 + sv0.x);
  float l0 = x0 > 0.f ? x0 : 0.2f * x0;
  float2 ec0 = make_float2(__expf(l0) * sv0.y, __int_as_float(cc.x << 7));

  if (e2 + 1 < E){
    if (rr.y != rr.x)
      for (int t = rr.x + 1; t <= rr.y; ++t) row_ptr[t] = e2 + 1;
    const float2 sv1 = s2v[cc.y];
    const float s11 = (rr.y == rr.x) ? s10 : sum1[rr.y];
    float x1 = av.y * (s11 + sv1.x);
    float l1 = x1 > 0.f ? x1 : 0.2f * x1;
    float2 ec1 = make_float2(__expf(l1) * sv1.y, __int_as_float(cc.y << 7));
    *(float4*)(excol + e2) = make_float4(ec0.x, ec0.y, ec1.x, ec1.y);
    if (e2 + 1 == E - 1)
      for (int t = rr.y + 1; t <= N; ++t) row_ptr[t] = E;
  } else {
    excol[e2] = ec0;
    for (int t = rr.x + 1; t <= N; ++t) row_ptr[t] = E;
  }
}

// One wave per row; single pass (LN2 scale-invariance cancels softmax 1/s; the
// +128 quant offset cancels in LN2 mean-subtraction — f32 roundoff analysis:
// sxx<=2e7, ulp 2 -> var rel err ~1e-4, negligible). Full-16 blocks unguarded;
// one guarded tail. (No inline asm — R5 lesson.)
__launch_bounds__(256)
__global__ void edge_kernel(const float2* __restrict__ excol, const int* __restrict__ row_ptr,
                            const unsigned char* __restrict__ value_q,
                            const float* __restrict__ ln2_g, const float* __restrict__ ln2_b,
                            float* __restrict__ out, int N){
  const int lane = threadIdx.x & 63;
  const int r = blockIdx.x * 4 + (threadIdx.x >> 6);
  if (r >= N) return;
  const int2 rp = *(const int2*)(row_ptr + r);   // one dwordx2: e0, e1
  const int e0 = rp.x, e1 = rp.y;
  const int q  = lane >> 4;   // quarter
  const int lq = lane & 15;   // owns dims [8*lq, 8*lq+8)
  const unsigned char* vbase = value_q + lq*8;

  f32x2 acc2[4];
  #pragma unroll
  for (int j = 0; j < 4; ++j) acc2[j] = (f32x2){0.f, 0.f};

  int sb = e0;
  for (; sb + 16 <= e1; sb += 16){           // full blocks: no guards
    #pragma unroll
    for (int t = 0; t < 4; ++t){
      float2 ecv = excol[sb + q + t*4];
      const float wsc = ecv.x;
      const unsigned voff = (unsigned)__float_as_int(ecv.y);
      uint2 v = *(const uint2*)(vbase + voff);
      f32x2 w2 = { wsc, wsc };
      f32x2 p0 = { (float)( v.x        & 0xff), (float)((v.x >>  8) & 0xff) };
      f32x2 p1 = { (float)((v.x >> 16) & 0xff), (float)( v.x >> 24)         };
      f32x2 p2 = { (float)( v.y        & 0xff), (float)((v.y >>  8) & 0xff) };
      f32x2 p3 = { (float)((v.y >> 16) & 0xff), (float)( v.y >> 24)         };
      acc2[0] += w2 * p0;
      acc2[1] += w2 * p1;
      acc2[2] += w2 * p2;
      acc2[3] += w2 * p3;
    }
  }
  if (sb < e1){                               // guarded tail (cnt%16 slots)
    #pragma unroll
    for (int t = 0; t < 4; ++t){
      const int e = sb + q + t*4;
      float2 ecv = (e < e1) ? excol[e] : make_float2(0.f, 0.f);  // voff 0 safe
      const float wsc = ecv.x;
      const unsigned voff = (unsigned)__float_as_int(ecv.y);
      uint2 v = *(const uint2*)(vbase + voff);
      f32x2 w2 = { wsc, wsc };
      f32x2 p0 = { (float)( v.x        & 0xff), (float)((v.x >>  8) & 0xff) };
      f32x2 p1 = { (float)((v.x >> 16) & 0xff), (float)( v.x >> 24)         };
      f32x2 p2 = { (float)( v.y        & 0xff), (float)((v.y >>  8) & 0xff) };
      f32x2 p3 = { (float)((v.y >> 16) & 0xff), (float)( v.y >> 24)         };
      acc2[0] += w2 * p0;
      acc2[1] += w2 * p1;
      acc2[2] += w2 * p2;
      acc2[3] += w2 * p3;
    }
  }

  // reduce across quarters (dims replicated 4x across wave)
  #pragma unroll
  for (int j = 0; j < 4; ++j){
    acc2[j].x += __shfl_xor(acc2[j].x, 16); acc2[j].y += __shfl_xor(acc2[j].y, 16);
    acc2[j].x += __shfl_xor(acc2[j].x, 32); acc2[j].y += __shfl_xor(acc2[j].y, 32);
  }

  // single-pass LN2 stats over 16 lanes (each dim once per quarter)
  float sx = 0.f, sxx = 0.f;
  #pragma unroll
  for (int j = 0; j < 4; ++j){
    sx  += acc2[j].x + acc2[j].y;
    sxx += acc2[j].x*acc2[j].x + acc2[j].y*acc2[j].y;
  }
  #pragma unroll
  for (int m = 1; m <= 8; m <<= 1){ sx += __shfl_xor(sx, m); sxx += __shfl_xor(sxx, m); }
  const float mean = sx * (1.f/128.f);
  const float var  = sxx * (1.f/128.f) - mean*mean;
  const float rs   = rsqrtf(var + EPS);

  if (q == 0){
    float4 g0 = ((const float4*)ln2_g)[lq*2], g1 = ((const float4*)ln2_g)[lq*2+1];
    float4 b0 = ((const float4*)ln2_b)[lq*2], b1 = ((const float4*)ln2_b)[lq*2+1];
    float4 o0, o1;
    o0.x = g0.x*(acc2[0].x-mean)*rs + b0.x; o0.y = g0.y*(acc2[0].y-mean)*rs + b0.y;
    o0.z = g0.z*(acc2[1].x-mean)*rs + b0.z; o0.w = g0.w*(acc2[1].y-mean)*rs + b0.w;
    o1.x = g1.x*(acc2[2].x-mean)*rs + b1.x; o1.y = g1.y*(acc2[2].y-mean)*rs + b1.y;
    o1.z = g1.z*(acc2[3].x-mean)*rs + b1.z; o1.w = g1.w*(acc2[3].y-mean)*rs + b1.w;
    float4* op = (float4*)(out + (size_t)r*DIM + lq*8);
    op[0] = o0; op[1] = o1;
  }
}

extern "C" void kernel_launch(void* const* d_in, const int* in_sizes, int n_in,
                              void* d_out, int out_size, void* d_ws, size_t ws_size,
                              hipStream_t stream){
  const float* query   = (const float*)d_in[0];
  const float* adj_val = (const float*)d_in[1];
  const float* w_W     = (const float*)d_in[2];
  const float* w_b     = (const float*)d_in[3];
  const float* w1_W    = (const float*)d_in[4];
  const float* w1_b    = (const float*)d_in[5];
  const float* w2_W    = (const float*)d_in[6];
  const float* w2_b    = (const float*)d_in[7];
  const float* ln1_g   = (const float*)d_in[8];
  const float* ln1_b   = (const float*)d_in[9];
  const float* ln2_g   = (const float*)d_in[10];
  const float* ln2_b   = (const float*)d_in[11];
  const int*   adj_row = (const int*)d_in[12];
  const int*   adj_col = (const int*)d_in[13];

  const int N = in_sizes[0] / DIM;
  const int E = in_sizes[1];

  char* ws = (char*)d_ws;
  size_t off = 0;
  unsigned char* value_q = (unsigned char*)(ws + off); off += (size_t)N * DIM;
  float* sum1   = (float*)(ws + off); off += (size_t)N * 4;
  float2* s2v   = (float2*)(ws + off); off += (size_t)N * 8;
  int* row_ptr  = (int*)(ws + off);   off += (size_t)(N + 2) * 4;
  float* u1     = (float*)(ws + off); off += DIM * 4;
  float* u2     = (float*)(ws + off); off += DIM * 4;
  float* c12    = (float*)(ws + off); off += 2 * 4;
  off = (off + 63) & ~(size_t)63;
  __hip_bfloat16* wt_bf = (__hip_bfloat16*)(ws + off); off += DIM * DIM * 2;
  off = (off + 63) & ~(size_t)63;
  float2* excol = (float2*)(ws + off);

  setup_kernel<<<65, 256, 0, stream>>>(w_W, w1_W, w1_b, w2_W, w2_b, wt_bf, u1, u2, c12);
  node_kernel<<<(N + 63) / 64, 256, 0, stream>>>(query, wt_bf, w_b, ln1_g, ln1_b,
                                                 u1, u2, c12, value_q, sum1, s2v, N);
  pack_kernel<<<(E/2 + 255) / 256, 256, 0, stream>>>(adj_val, adj_row, adj_col,
                                                     sum1, s2v, excol, row_ptr, N, E);
  edge_kernel<<<(N + 3) / 4, 256, 0, stream>>>(excol, row_ptr, value_q,
                                               ln2_g, ln2_b, (float*)d_out, N);
}

// Round 9
// 93.131 us; speedup vs baseline: 1.4286x; 1.1338x over previous
//
#include <hip/hip_runtime.h>
#include <hip/hip_bf16.h>

typedef __attribute__((ext_vector_type(8))) short short8;
typedef __attribute__((ext_vector_type(8))) unsigned short ushort8;
typedef __attribute__((ext_vector_type(4))) float f32x4;
typedef __attribute__((ext_vector_type(2))) float f32x2;
typedef __attribute__((ext_vector_type(4))) unsigned int uint4v;

#define DIM 128
#define EPS 1e-6f

__device__ __forceinline__ float wave_sum(float v){
  #pragma unroll
  for (int m = 32; m >= 1; m >>= 1) v += __shfl_xor(v, m);
  return v;
}

// One launch: block 0 = u1/u2/c12; blocks 1..64 = W^T bf16.
__global__ void setup_kernel(const float* __restrict__ w_W,
                             const float* __restrict__ w1_W, const float* __restrict__ w1_b,
                             const float* __restrict__ w2_W, const float* __restrict__ w2_b,
                             __hip_bfloat16* __restrict__ wt_bf,
                             float* __restrict__ u1, float* __restrict__ u2,
                             float* __restrict__ c12){
  const int b = blockIdx.x, tid = threadIdx.x;
  if (b == 0){
    __shared__ float p1s[256], p2s[256];
    const int d = tid & 127, half = tid >> 7;       // half 0: j 0..63, half 1: j 64..127
    const float4* w1p = (const float4*)(w1_W + d*DIM + half*64);
    const float4* w2p = (const float4*)(w2_W + d*DIM + half*64);
    float s1 = 0.f, s2 = 0.f;
    #pragma unroll 4
    for (int j = 0; j < 16; ++j){
      float4 a = w1p[j]; s1 += (a.x + a.y) + (a.z + a.w);
      float4 c = w2p[j]; s2 += (c.x + c.y) + (c.z + c.w);
    }
    p1s[tid] = s1; p2s[tid] = s2;
    __syncthreads();
    if (tid < 128){ u1[tid] = p1s[tid] + p1s[tid+128]; u2[tid] = p2s[tid] + p2s[tid+128]; }
    if (tid < 64){
      float c1 = w1_b[tid] + w1_b[tid + 64];
      float c2 = w2_b[tid] + w2_b[tid + 64];
      c1 = wave_sum(c1); c2 = wave_sum(c2);
      if (tid == 0){ c12[0] = c1; c12[1] = c2; }
    }
  } else {
    int idx = (b - 1) * 256 + tid;
    int j = idx >> 7, d = idx & 127;
    wt_bf[idx] = __float2bfloat16(w_W[d*DIM + j]);
  }
}

// LN1 (16-lane group per node) + value = q@w_W + w_b (bf16 MFMA; wave = 32 rows x 64 cols)
// + per-row int8 quantization of value. Writes sum1, s2v = {tanh2, scale}.
__launch_bounds__(256)
__global__ void node_kernel(const float* __restrict__ query,
                            const __hip_bfloat16* __restrict__ wt_bf,
                            const float* __restrict__ w_b,
                            const float* __restrict__ ln1_g, const float* __restrict__ ln1_b,
                            const float* __restrict__ u1, const float* __restrict__ u2,
                            const float* __restrict__ c12,
                            unsigned char* __restrict__ value_q,
                            float* __restrict__ sum1, float2* __restrict__ s2v, int N){
  __shared__ __hip_bfloat16 A[64][136];    // +8 pad; row stride 272B (16B aligned)
  const int tid  = threadIdx.x;
  const int lane = tid & 63;
  const int w    = tid >> 6;
  const int q16  = lane >> 4;    // group 0..3
  const int lq   = lane & 15;    // lane in group
  const int base = blockIdx.x * 64;

  float uu1[8], uu2[8], gg[8], bv[8];
  {
    const float* p1 = u1 + lq*8; const float* p2 = u2 + lq*8;
    const float* pg = ln1_g + lq*8; const float* pb = ln1_b + lq*8;
    #pragma unroll
    for (int j = 0; j < 8; ++j){ uu1[j]=p1[j]; uu2[j]=p2[j]; gg[j]=pg[j]; bv[j]=pb[j]; }
  }
  const float c1 = c12[0], c2 = c12[1];

  // LN1: group q16 of wave w handles node base + w*16 + it*4 + q16
  #pragma unroll
  for (int it = 0; it < 4; ++it){
    const int row = w*16 + it*4 + q16;
    const int n   = base + row;
    float x[8];
    if (n < N){
      const float4* qp = (const float4*)(query + (size_t)n*DIM + lq*8);
      float4 a = qp[0], b = qp[1];
      x[0]=a.x; x[1]=a.y; x[2]=a.z; x[3]=a.w;
      x[4]=b.x; x[5]=b.y; x[6]=b.z; x[7]=b.w;
    } else {
      #pragma unroll
      for (int j = 0; j < 8; ++j) x[j] = 0.f;
    }
    float s = 0.f, s2 = 0.f;
    #pragma unroll
    for (int j = 0; j < 8; ++j){ s += x[j]; s2 += x[j]*x[j]; }
    #pragma unroll
    for (int m = 1; m <= 8; m <<= 1){ s += __shfl_xor(s, m); s2 += __shfl_xor(s2, m); }
    const float mean = s * (1.f/128.f);
    const float var  = s2 * (1.f/128.f) - mean*mean;
    const float rs   = rsqrtf(var + EPS);

    float p1 = 0.f, p2 = 0.f;
    unsigned pk[4];
    #pragma unroll
    for (int j = 0; j < 4; ++j){
      float n0 = gg[2*j]   * (x[2*j]   - mean) * rs + bv[2*j];
      float n1 = gg[2*j+1] * (x[2*j+1] - mean) * rs + bv[2*j+1];
      p1 += n0*uu1[2*j] + n1*uu1[2*j+1];
      p2 += n0*uu2[2*j] + n1*uu2[2*j+1];
      union { __hip_bfloat16 h; unsigned short u; } a_, b_;
      a_.h = __float2bfloat16(n0); b_.h = __float2bfloat16(n1);
      pk[j] = ((unsigned)b_.u << 16) | (unsigned)a_.u;
    }
    uint4v pv = { pk[0], pk[1], pk[2], pk[3] };
    *(uint4v*)&A[row][lq*8] = pv;
    #pragma unroll
    for (int m = 1; m <= 8; m <<= 1){ p1 += __shfl_xor(p1, m); p2 += __shfl_xor(p2, m); }
    if (lq == 0 && n < N){
      sum1[n]   = tanhf(p1 + c1);
      s2v[n].x  = tanhf(p2 + c2);
    }
  }
  __syncthreads();

  // GEMM: wave w: rows [(w&1)*32, +32) x cols [(w>>1)*64, +64); 2 MFMA per B-load
  const int rh = (w & 1) * 32;
  const int ch = (w >> 1) * 64;
  short8 afr[2][4];
  #pragma unroll
  for (int m = 0; m < 2; ++m)
    #pragma unroll
    for (int ks = 0; ks < 4; ++ks)
      afr[m][ks] = *(const short8*)&A[rh + m*16 + lq][ks*32 + q16*8];
  __syncthreads();   // all waves done reading A before C overwrites it

  #pragma unroll
  for (int jj = 0; jj < 4; ++jj){
    const int colb = ch + jj*16;
    f32x4 acc[2];
    acc[0] = (f32x4){0.f,0.f,0.f,0.f};
    acc[1] = (f32x4){0.f,0.f,0.f,0.f};
    #pragma unroll
    for (int ks = 0; ks < 4; ++ks){
      short8 bfr = *(const short8*)(wt_bf + (size_t)(colb + lq)*DIM + ks*32 + q16*8);
      acc[0] = __builtin_amdgcn_mfma_f32_16x16x32_bf16(afr[0][ks], bfr, acc[0], 0, 0, 0);
      acc[1] = __builtin_amdgcn_mfma_f32_16x16x32_bf16(afr[1][ks], bfr, acc[1], 0, 0, 0);
    }
    const int col  = colb + lq;            // C/D: col = lane&15, row = (lane>>4)*4 + reg
    const float bias = w_b[col];
    #pragma unroll
    for (int m = 0; m < 2; ++m)
      #pragma unroll
      for (int i = 0; i < 4; ++i)
        A[rh + m*16 + q16*4 + i][col] = __float2bfloat16(acc[m][i] + bias);
  }
  __syncthreads();

  // int8 quantize + store: 4 threads per row; vectorized ds_read_b128 (16B x4)
  const int row = tid >> 2, seg = tid & 3;
  const int n = base + row;
  float vals[32];
  float amax = 0.f;
  const ushort8* ap = (const ushort8*)&A[row][seg*32];
  #pragma unroll
  for (int h = 0; h < 4; ++h){
    ushort8 vv = ap[h];
    #pragma unroll
    for (int j = 0; j < 8; ++j){
      float f = __uint_as_float((unsigned)vv[j] << 16);
      vals[h*8 + j] = f;
      amax = fmaxf(amax, fabsf(f));
    }
  }
  amax = fmaxf(amax, __shfl_xor(amax, 1));
  amax = fmaxf(amax, __shfl_xor(amax, 2));
  const float qs = amax > 0.f ? 127.f / amax : 0.f;
  if (n < N){
    if (seg == 0) s2v[n].y = amax * (1.f/127.f);
    unsigned dw[8];
    #pragma unroll
    for (int d = 0; d < 8; ++d){
      unsigned q0 = (unsigned)__float2int_rn(fmaf(vals[4*d+0], qs, 128.f));
      unsigned q1 = (unsigned)__float2int_rn(fmaf(vals[4*d+1], qs, 128.f));
      unsigned q2 = (unsigned)__float2int_rn(fmaf(vals[4*d+2], qs, 128.f));
      unsigned q3 = (unsigned)__float2int_rn(fmaf(vals[4*d+3], qs, 128.f));
      dw[d] = q0 | (q1 << 8) | (q2 << 16) | (q3 << 24);
    }
    uint4v* dst = (uint4v*)(value_q + (size_t)n*DIM + seg*32);
    dst[0] = (uint4v){dw[0], dw[1], dw[2], dw[3]};
    dst[1] = (uint4v){dw[4], dw[5], dw[6], dw[7]};
  }
}

// Per-edge: row_ptr via boundary detect (adj_row sorted) + excol = {ws, byteoff}
// ws = exp(leaky(av*(s1[r]+s2[c]))) * s_val[c];  byteoff = c*128 (pre-shifted).
__global__ void pack_kernel(const float* __restrict__ adj_val, const int* __restrict__ adj_row,
                            const int* __restrict__ adj_col,
                            const float* __restrict__ sum1, const float2* __restrict__ s2v,
                            float2* __restrict__ excol, int* __restrict__ row_ptr,
                            int N, int E){
  int e = blockIdx.x * 256 + threadIdx.x;
  if (e >= E) return;
  int r  = adj_row[e];
  int rp = (e > 0) ? adj_row[e-1] : -1;
  if (rp != r){
    for (int rr = rp + 1; rr <= r; ++rr) row_ptr[rr] = e;
  }
  if (e == E - 1){
    for (int rr = r + 1; rr <= N; ++rr) row_ptr[rr] = E;
  }
  float av = adj_val[e];
  int c = adj_col[e];
  float2 sv = s2v[c];          // one 8B gather: {tanh2, scale}
  float x = av * (sum1[r] + sv.x);
  float lg = x > 0.f ? x : 0.2f * x;
  excol[e] = make_float2(__expf(lg) * sv.y, __int_as_float(c << 7));
}

// TWO rows per wave (lanes 0-31 = row A, 32-63 = row B); 2 sixteen-lane quarters
// per row -> block granularity 8 edges; per-row fixed cost (reduce/stats/epilogue)
// halved vs 1-row/wave. Single pass (LN2 scale-invariance cancels softmax 1/s;
// +128 quant offset cancels in mean-subtraction, roundoff ~1e-4 relative).
// All shuffles stay within 32-lane halves (xor 16, xor m<=8).
__launch_bounds__(256)
__global__ void edge_kernel(const float2* __restrict__ excol, const int* __restrict__ row_ptr,
                            const unsigned char* __restrict__ value_q,
                            const float* __restrict__ ln2_g, const float* __restrict__ ln2_b,
                            float* __restrict__ out, int N){
  const int lane = threadIdx.x & 63;
  const int half = lane >> 5;          // row within the wave's pair
  const int ll   = lane & 31;
  const int q2   = ll >> 4;            // quarter within row (0/1)
  const int lq   = ll & 15;            // owns dims [8*lq, 8*lq+8)
  const int r = blockIdx.x * 8 + (threadIdx.x >> 6) * 2 + half;
  if (r >= N) return;
  const int2 rp = *(const int2*)(row_ptr + r);   // e0, e1
  const int e0 = rp.x, e1 = rp.y;
  const unsigned char* vbase = value_q + lq*8;

  f32x2 acc2[4];
  #pragma unroll
  for (int j = 0; j < 4; ++j) acc2[j] = (f32x2){0.f, 0.f};

  int sb = e0;
  for (; sb + 8 <= e1; sb += 8){           // full 8-blocks: no guards
    #pragma unroll
    for (int t = 0; t < 4; ++t){
      float2 ecv = excol[sb + q2 + t*2];
      const float wsc = ecv.x;
      const unsigned voff = (unsigned)__float_as_int(ecv.y);
      uint2 v = *(const uint2*)(vbase + voff);
      f32x2 w2 = { wsc, wsc };
      f32x2 p0 = { (float)( v.x        & 0xff), (float)((v.x >>  8) & 0xff) };
      f32x2 p1 = { (float)((v.x >> 16) & 0xff), (float)( v.x >> 24)         };
      f32x2 p2 = { (float)( v.y        & 0xff), (float)((v.y >>  8) & 0xff) };
      f32x2 p3 = { (float)((v.y >> 16) & 0xff), (float)( v.y >> 24)         };
      acc2[0] += w2 * p0;
      acc2[1] += w2 * p1;
      acc2[2] += w2 * p2;
      acc2[3] += w2 * p3;
    }
  }
  if (sb < e1){                             // guarded tail (cnt%8 slots)
    #pragma unroll
    for (int t = 0; t < 4; ++t){
      const int e = sb + q2 + t*2;
      float2 ecv = (e < e1) ? excol[e] : make_float2(0.f, 0.f);  // voff 0 safe
      const float wsc = ecv.x;
      const unsigned voff = (unsigned)__float_as_int(ecv.y);
      uint2 v = *(const uint2*)(vbase + voff);
      f32x2 w2 = { wsc, wsc };
      f32x2 p0 = { (float)( v.x        & 0xff), (float)((v.x >>  8) & 0xff) };
      f32x2 p1 = { (float)((v.x >> 16) & 0xff), (float)( v.x >> 24)         };
      f32x2 p2 = { (float)( v.y        & 0xff), (float)((v.y >>  8) & 0xff) };
      f32x2 p3 = { (float)((v.y >> 16) & 0xff), (float)( v.y >> 24)         };
      acc2[0] += w2 * p0;
      acc2[1] += w2 * p1;
      acc2[2] += w2 * p2;
      acc2[3] += w2 * p3;
    }
  }

  // reduce across the 2 quarters of this row (stays within the 32-lane half)
  #pragma unroll
  for (int j = 0; j < 4; ++j){
    acc2[j].x += __shfl_xor(acc2[j].x, 16);
    acc2[j].y += __shfl_xor(acc2[j].y, 16);
  }

  // single-pass LN2 stats over the 16-lane dim groups (both rows simultaneously)
  float sx = 0.f, sxx = 0.f;
  #pragma unroll
  for (int j = 0; j < 4; ++j){
    sx  += acc2[j].x + acc2[j].y;
    sxx += acc2[j].x*acc2[j].x + acc2[j].y*acc2[j].y;
  }
  #pragma unroll
  for (int m = 1; m <= 8; m <<= 1){ sx += __shfl_xor(sx, m); sxx += __shfl_xor(sxx, m); }
  const float mean = sx * (1.f/128.f);
  const float var  = sxx * (1.f/128.f) - mean*mean;
  const float rs   = rsqrtf(var + EPS);

  if (q2 == 0){
    float4 g0 = ((const float4*)ln2_g)[lq*2], g1 = ((const float4*)ln2_g)[lq*2+1];
    float4 b0 = ((const float4*)ln2_b)[lq*2], b1 = ((const float4*)ln2_b)[lq*2+1];
    float4 o0, o1;
    o0.x = g0.x*(acc2[0].x-mean)*rs + b0.x; o0.y = g0.y*(acc2[0].y-mean)*rs + b0.y;
    o0.z = g0.z*(acc2[1].x-mean)*rs + b0.z; o0.w = g0.w*(acc2[1].y-mean)*rs + b0.w;
    o1.x = g1.x*(acc2[2].x-mean)*rs + b1.x; o1.y = g1.y*(acc2[2].y-mean)*rs + b1.y;
    o1.z = g1.z*(acc2[3].x-mean)*rs + b1.z; o1.w = g1.w*(acc2[3].y-mean)*rs + b1.w;
    float4* op = (float4*)(out + (size_t)r*DIM + lq*8);
    op[0] = o0; op[1] = o1;
  }
}

extern "C" void kernel_launch(void* const* d_in, const int* in_sizes, int n_in,
                              void* d_out, int out_size, void* d_ws, size_t ws_size,
                              hipStream_t stream){
  const float* query   = (const float*)d_in[0];
  const float* adj_val = (const float*)d_in[1];
  const float* w_W     = (const float*)d_in[2];
  const float* w_b     = (const float*)d_in[3];
  const float* w1_W    = (const float*)d_in[4];
  const float* w1_b    = (const float*)d_in[5];
  const float* w2_W    = (const float*)d_in[6];
  const float* w2_b    = (const float*)d_in[7];
  const float* ln1_g   = (const float*)d_in[8];
  const float* ln1_b   = (const float*)d_in[9];
  const float* ln2_g   = (const float*)d_in[10];
  const float* ln2_b   = (const float*)d_in[11];
  const int*   adj_row = (const int*)d_in[12];
  const int*   adj_col = (const int*)d_in[13];

  const int N = in_sizes[0] / DIM;
  const int E = in_sizes[1];

  char* ws = (char*)d_ws;
  size_t off = 0;
  unsigned char* value_q = (unsigned char*)(ws + off); off += (size_t)N * DIM;
  float* sum1   = (float*)(ws + off); off += (size_t)N * 4;
  float2* s2v   = (float2*)(ws + off); off += (size_t)N * 8;
  int* row_ptr  = (int*)(ws + off);   off += (size_t)(N + 2) * 4;
  float* u1     = (float*)(ws + off); off += DIM * 4;
  float* u2     = (float*)(ws + off); off += DIM * 4;
  float* c12    = (float*)(ws + off); off += 2 * 4;
  off = (off + 63) & ~(size_t)63;
  __hip_bfloat16* wt_bf = (__hip_bfloat16*)(ws + off); off += DIM * DIM * 2;
  off = (off + 63) & ~(size_t)63;
  float2* excol = (float2*)(ws + off);

  setup_kernel<<<65, 256, 0, stream>>>(w_W, w1_W, w1_b, w2_W, w2_b, wt_bf, u1, u2, c12);
  node_kernel<<<(N + 63) / 64, 256, 0, stream>>>(query, wt_bf, w_b, ln1_g, ln1_b,
                                                 u1, u2, c12, value_q, sum1, s2v, N);
  pack_kernel<<<(E + 255) / 256, 256, 0, stream>>>(adj_val, adj_row, adj_col,
                                                   sum1, s2v, excol, row_ptr, N, E);
  edge_kernel<<<(N + 7) / 8, 256, 0, stream>>>(excol, row_ptr, value_q,
                                               ln2_g, ln2_b, (float*)d_out, N);
}